// Round 2
// baseline (32.998 us; speedup 1.0000x reference)
//
#include <hip/hip_runtime.h>
#include <math.h>

// out = sigmoid( ts^2 * sum_b ( h0*T_all_b + c1_b*T_valid_b + bias )^2 )
//   T_all_b  = sum_{n<N}  dot(x[b,n,:], W)
//   T_valid_b= sum_{n<nv} dot(x[b,n,:], W)
//   c1_b = h1*(nv-1) + h2*(nv-1)^2
// (U p(L) U^T == p(A); A = J-I on the valid block, A^2 = (nv-2)J + I there.)
//
// Single fused kernel: per-block partial -> threadfence -> atomic ticket ->
// last-arriving block reduces partials in FIXED order (deterministic value)
// and writes the sigmoid. Ticket counter zeroed per call via hipMemsetAsync.

__global__ __launch_bounds__(256) void sgc_fused_kernel(
    const float* __restrict__ x,
    const int*   __restrict__ nnodes,
    const float* __restrict__ h,
    const float* __restrict__ W,
    const float* __restrict__ bias,
    const float* __restrict__ ts,
    float*       __restrict__ out,
    float*       __restrict__ partial,
    unsigned int* __restrict__ counter,
    int B, int N, int F, int nBlocks)
{
    const int wave = threadIdx.x >> 6;   // 4 waves / block, one batch each
    const int lane = threadIdx.x & 63;   // lane = node index
    const int b    = blockIdx.x * 4 + wave;

    __shared__ float sblk[4];
    __shared__ int   isLast;

    float sq = 0.0f;
    if (b < B) {
        const float h0 = h[0], h1 = h[1], h2 = h[2];
        const int   nv = nnodes[b];                 // wave-uniform
        const float m  = (float)(nv - 1);
        const float c1 = h1 * m + h2 * m * m;

        float d = 0.0f;
        if (lane < N) {
            const float* xp = x + ((size_t)b * N + lane) * F;
            float acc = 0.0f;
            if (F == 7) {
                #pragma unroll
                for (int f = 0; f < 7; ++f) acc = fmaf(xp[f], W[f], acc);
            } else {
                for (int f = 0; f < F; ++f) acc = fmaf(xp[f], W[f], acc);
            }
            d = acc * (h0 + ((lane < nv) ? c1 : 0.0f));
        }
        #pragma unroll
        for (int off = 32; off > 0; off >>= 1)
            d += __shfl_down(d, off, 64);

        if (lane == 0) {
            const float ob = d + bias[0];
            sq = ob * ob;
        }
    }
    if (lane == 0) sblk[wave] = sq;
    __syncthreads();

    if (threadIdx.x == 0) {
        partial[blockIdx.x] = sblk[0] + sblk[1] + sblk[2] + sblk[3];
        __threadfence();                             // release partial[]
        unsigned t = atomicAdd(counter, 1u);         // device-scope ticket
        isLast = (t == (unsigned)(nBlocks - 1)) ? 1 : 0;
    }
    __syncthreads();

    if (isLast) {
        __threadfence();                             // acquire partial[]
        float v = 0.0f;
        for (int i = threadIdx.x; i < nBlocks; i += 256)  // fixed order
            v += partial[i];
        #pragma unroll
        for (int off = 32; off > 0; off >>= 1)
            v += __shfl_down(v, off, 64);
        if (lane == 0) sblk[wave] = v;
        __syncthreads();
        if (threadIdx.x == 0) {
            const float total = sblk[0] + sblk[1] + sblk[2] + sblk[3];
            const float t0  = ts[0];
            const float arg = t0 * t0 * total;       // >= 0 always
            out[0] = 1.0f / (1.0f + expf(-arg));
        }
    }
}

extern "C" void kernel_launch(void* const* d_in, const int* in_sizes, int n_in,
                              void* d_out, int out_size, void* d_ws, size_t ws_size,
                              hipStream_t stream) {
    const float* x    = (const float*)d_in[0];
    const int*   nn   = (const int*)  d_in[1];
    const float* h    = (const float*)d_in[2];
    const float* W    = (const float*)d_in[3];
    const float* bias = (const float*)d_in[4];
    const float* ts   = (const float*)d_in[5];

    const int B = in_sizes[1];            // number_of_nodes has B entries
    const int F = in_sizes[3];            // W has F entries
    const int N = in_sizes[0] / (B * F);  // x is [B, N, F]

    unsigned int* counter = (unsigned int*)d_ws;            // 4 B @ offset 0
    float*        partial = (float*)((char*)d_ws + 256);    // aligned past it

    const int grid = (B + 3) / 4;         // 4 batches (waves) per block

    hipMemsetAsync(counter, 0, sizeof(unsigned int), stream);
    sgc_fused_kernel<<<grid, 256, 0, stream>>>(
        x, nn, h, W, bias, ts, (float*)d_out, partial, counter, B, N, F, grid);
}